// Round 10
// baseline (8284.090 us; speedup 1.0000x reference)
//
#include <hip/hip_runtime.h>
#include <math.h>

#define DM    512
#define SP    1568   // 8*14*14
#define BATCH 32
#define NSTEP 12
#define CPAD  2560   // padded per-batch spatial rows (10*16*16)
#define LDT   40     // kproj-GEMM LDS row stride (bf16)
#define LDT2  72     // conv BK=64 LDS row stride (bf16)
#define ILS   520    // fused kernel LDS row stride (bf16)

typedef short s16x8 __attribute__((ext_vector_type(8)));
typedef float f32x4 __attribute__((ext_vector_type(4)));

__device__ __forceinline__ float eluf(float x) { return x > 0.f ? x : expf(x) - 1.f; }
__device__ __forceinline__ float b2f(ushort u) {
  union { float f; unsigned i; } v; v.i = ((unsigned)u) << 16; return v.f;
}
__device__ __forceinline__ ushort f2b(float f) {
  union { float f; unsigned i; } v; v.f = f;
  unsigned r = (v.i + 0x7FFFu + ((v.i >> 16) & 1u)) >> 16;
  return (ushort)r;
}

// ---------------------------------------------------------------------------
__global__ void k_zero(uint4* __restrict__ p, long n16) {
  long stride = (long)gridDim.x * blockDim.x;
  for (long i = (long)blockIdx.x * blockDim.x + threadIdx.x; i < n16; i += stride)
    p[i] = make_uint4(0, 0, 0, 0);
}

// image [32][256][1568] fp32 -> NHWC padded bf16 [b][2560][256] (interior only)
__global__ void k_padimg(const float* __restrict__ img, ushort* __restrict__ xp) {
  int blk = blockIdx.x;                 // 32*1568
  int b = blk / SP, s = blk - b * SP;
  int ci = threadIdx.x;                 // 256
  int z = s / 196, r = s - z * 196, y = r / 14, x = r - y * 14;
  int p = (z + 1) * 256 + (y + 1) * 16 + (x + 1);
  xp[((size_t)b * CPAD + p) * 256 + ci] = f2b(img[((size_t)b * 256 + ci) * SP + s]);
}

// conv weights [co][ci][27] fp32 -> tap-major bf16 [co][tap*CIN+ci]
template <int CIN>
__global__ void k_cvtw(const float* __restrict__ w, ushort* __restrict__ o) {
  int idx = blockIdx.x * 256 + threadIdx.x;   // < 512*27*CIN
  const int KK = 27 * CIN;
  int co = idx / KK; int rem = idx - co * KK;
  int tap = rem / CIN; int ci = rem - tap * CIN;
  o[idx] = f2b(w[((size_t)co * CIN + ci) * 27 + tap]);
}

// [512][512] fp32 -> transposed bf16 [n][k]
__global__ void k_cvtT(const float* __restrict__ w, ushort* __restrict__ o) {
  int idx = blockIdx.x * 256 + threadIdx.x;   // < 512*512
  int n = idx >> 9, k = idx & 511;
  o[idx] = f2b(w[(size_t)k * 512 + n]);
}

// ---------------------------------------------------------------------------
// MFMA conv3d, NHWC activations, BK=64 (unchanged)
// ---------------------------------------------------------------------------
template <int CIN, int ISCONV1>
__global__ __launch_bounds__(256) void k_convm(
    const ushort* __restrict__ W, const ushort* __restrict__ Xp,
    const float* __restrict__ bias, ushort* __restrict__ Y)
{
  const int KK = CIN * 27;
  const int b  = blockIdx.z;
  const int n0 = blockIdx.x * 128;
  const int m0 = blockIdx.y * 128;
  __shared__ __align__(16) ushort As[128 * LDT2];
  __shared__ __align__(16) ushort Bs[128 * LDT2];
  const int t = threadIdx.x;
  const int lane = t & 63, wid = t >> 6;
  const int wm = (wid >> 1) * 64, wn = (wid & 1) * 64;
  const int l15 = lane & 15, quad = lane >> 4;
  f32x4 acc[4][4];
#pragma unroll
  for (int i = 0; i < 4; i++)
#pragma unroll
    for (int j = 0; j < 4; j++) acc[i][j] = (f32x4){0.f, 0.f, 0.f, 0.f};

  for (int k0 = 0; k0 < KK; k0 += 64) {
#pragma unroll
    for (int i = 0; i < 4; i++) {          // A tile: 128co x 64k
      int f = t + i * 256;
      int row = f >> 3, ko = (f & 7) * 8;
      uint4 v = *(const uint4*)&W[(size_t)(m0 + row) * KK + k0 + ko];
      *(uint4*)&As[row * LDT2 + ko] = v;
    }
    {                                       // B tile: fixed tap, NHWC, 64 ci
      int tap = k0 / CIN, ci0 = k0 - tap * CIN;
      int dz = tap / 9, rr = tap - dz * 9, dy = rr / 3, dx = rr - dy * 3;
      int tofs = dz * 256 + dy * 16 + dx;
      const ushort* src = Xp + ((size_t)b * CPAD + tofs + n0) * CIN + ci0;
#pragma unroll
      for (int i = 0; i < 4; i++) {
        int f = t + i * 256;
        int row = f >> 3, ko = (f & 7) * 8;
        uint4 v = *(const uint4*)&src[(size_t)row * CIN + ko];
        *(uint4*)&Bs[row * LDT2 + ko] = v;
      }
    }
    __syncthreads();
#pragma unroll
    for (int sub = 0; sub < 2; sub++) {
      s16x8 af[4], bfr[4];
#pragma unroll
      for (int i = 0; i < 4; i++)
        af[i] = *(const s16x8*)&As[(wm + i * 16 + l15) * LDT2 + sub * 32 + quad * 8];
#pragma unroll
      for (int j = 0; j < 4; j++)
        bfr[j] = *(const s16x8*)&Bs[(wn + j * 16 + l15) * LDT2 + sub * 32 + quad * 8];
#pragma unroll
      for (int i = 0; i < 4; i++)
#pragma unroll
        for (int j = 0; j < 4; j++)
          acc[i][j] = __builtin_amdgcn_mfma_f32_16x16x32_bf16(af[i], bfr[j], acc[i][j], 0, 0, 0);
    }
    __syncthreads();
  }

#pragma unroll
  for (int i = 0; i < 4; i++) {
    int cob = m0 + wm + i * 16 + quad * 4;
    float4 bb = *(const float4*)&bias[cob];
#pragma unroll
    for (int j = 0; j < 4; j++) {
      int n = n0 + wn + j * 16 + l15;
      int z = n >> 8, y = (n >> 4) & 15, x = n & 15;
      if (y < 14 && x < 14) {
        ushort4 o;
        o.x = f2b(eluf(acc[i][j][0] + bb.x));
        o.y = f2b(eluf(acc[i][j][1] + bb.y));
        o.z = f2b(eluf(acc[i][j][2] + bb.z));
        o.w = f2b(eluf(acc[i][j][3] + bb.w));
        if (ISCONV1) {
          *(ushort4*)&Y[((size_t)b * CPAD + n + 273) * 512 + cob] = o;
        } else {
          int s = z * 196 + y * 14 + x;
          *(ushort4*)&Y[((size_t)b * SP + s) * DM + cob] = o;
        }
      }
    }
  }
}

// ---------------------------------------------------------------------------
// MFMA GEMM: kproj = know @ WkT + bk (unchanged)
// ---------------------------------------------------------------------------
__global__ __launch_bounds__(256) void k_gemmm(
    const ushort* __restrict__ A0, const ushort* __restrict__ Bt,
    const float* __restrict__ bias, ushort* __restrict__ Cv)
{
  const int bq = blockIdx.z;
  const int m0 = blockIdx.x * 128;
  const int n0 = blockIdx.y * 128;
  const ushort* A = A0 + (size_t)bq * SP * DM;
  __shared__ __align__(16) ushort As[128 * LDT];
  __shared__ __align__(16) ushort Bs[128 * LDT];
  const int t = threadIdx.x;
  const int lane = t & 63, wid = t >> 6;
  const int wm = (wid >> 1) * 64, wn = (wid & 1) * 64;
  const int l15 = lane & 15, quad = lane >> 4;
  f32x4 acc[4][4];
#pragma unroll
  for (int i = 0; i < 4; i++)
#pragma unroll
    for (int j = 0; j < 4; j++) acc[i][j] = (f32x4){0.f, 0.f, 0.f, 0.f};

  for (int k0 = 0; k0 < DM; k0 += 32) {
#pragma unroll
    for (int i = 0; i < 2; i++) {
      int f = t + i * 256;
      int row = f >> 2, ko = (f & 3) * 8;
      int mg = m0 + row;
      uint4 v = make_uint4(0, 0, 0, 0);
      if (mg < SP) v = *(const uint4*)&A[(size_t)mg * DM + k0 + ko];
      *(uint4*)&As[row * LDT + ko] = v;
      uint4 w = *(const uint4*)&Bt[(size_t)(n0 + row) * DM + k0 + ko];
      *(uint4*)&Bs[row * LDT + ko] = w;
    }
    __syncthreads();
    s16x8 af[4], bfr[4];
#pragma unroll
    for (int i = 0; i < 4; i++)
      af[i] = *(const s16x8*)&As[(wm + i * 16 + l15) * LDT + quad * 8];
#pragma unroll
    for (int j = 0; j < 4; j++)
      bfr[j] = *(const s16x8*)&Bs[(wn + j * 16 + l15) * LDT + quad * 8];
#pragma unroll
    for (int i = 0; i < 4; i++)
#pragma unroll
      for (int j = 0; j < 4; j++)
        acc[i][j] = __builtin_amdgcn_mfma_f32_16x16x32_bf16(af[i], bfr[j], acc[i][j], 0, 0, 0);
    __syncthreads();
  }

  ushort* C = Cv + (size_t)bq * SP * DM;
#pragma unroll
  for (int j = 0; j < 4; j++) {
    int n = n0 + wn + j * 16 + l15;
    float bb = bias[n];
#pragma unroll
    for (int i = 0; i < 4; i++) {
      int mb = m0 + wm + i * 16 + quad * 4;
#pragma unroll
      for (int r = 0; r < 4; r++) {
        int m = mb + r;
        if (m < SP) C[(size_t)m * DM + n] = f2b(acc[i][j][r] + bb);
      }
    }
  }
}

// ---------------------------------------------------------------------------
// Fused ReadUnit GEMM pair v6 — v4 config (Af+Il in LDS, 16 waves, 137 KB,
// 4 waves/SIMD) with WIDE 32m x 64n wave tiles in BOTH stages:
// 16 waves = 2 m-halves x 8 n-slices; per k-chunk/wave: 2 LDS A-frags +
// 4 global B-frags + 8 MFMA (4x less LDS traffic per MFMA than v4).
// befft is read once per m-half (2x per block; 2nd hits L1/L2).
// Grid (25, 32), 1024 threads, 2 barriers.
// ---------------------------------------------------------------------------
__global__ __launch_bounds__(1024, 4) void k_fused12(
    const ushort* __restrict__ kproj, const ushort* __restrict__ befft,
    const ushort* __restrict__ wc2t, const float* __restrict__ bcat,
    const float* __restrict__ bcat2, const float* __restrict__ cbuf,
    const float* __restrict__ raw, float* __restrict__ rl)
{
  extern __shared__ __align__(16) char smem[];
  ushort* Af  = (ushort*)smem;                 // 64*520 (kproj tile)
  ushort* Il  = Af + 64 * ILS;                 // 64*520 (inter1)
  float*  red = (float*)(Il + 64 * ILS);       // 64*8

  const int b  = blockIdx.y;
  const int m0 = blockIdx.x * 64;
  const int t  = threadIdx.x;
  const int lane = t & 63, w = t >> 6;         // 16 waves
  const int h = w >> 3, ws = w & 7;            // m-half, n-slice
  const int l15 = lane & 15, quad = lane >> 4;

  const ushort* kpb = kproj + (size_t)b * SP * DM;
#pragma unroll
  for (int i = 0; i < 4; i++) {
    int f = t + i * 1024;                      // < 4096 uint4 chunks
    int row = f >> 6, ch = (f & 63) * 8;
    int mg = m0 + row;
    uint4 v = make_uint4(0, 0, 0, 0);
    if (mg < SP) v = *(const uint4*)&kpb[(size_t)mg * DM + ch];
    *(uint4*)&Af[row * ILS + ch] = v;
  }
  __syncthreads();

  // ---- stage A: 16 k-chunks, wave tile 32m x 64n, no internal barriers ----
  const ushort* bfb = befft + (size_t)b * DM * DM;
  f32x4 acc[2][4];
#pragma unroll
  for (int i = 0; i < 2; i++)
#pragma unroll
    for (int j = 0; j < 4; j++) acc[i][j] = (f32x4){0.f, 0.f, 0.f, 0.f};
#pragma unroll 4
  for (int k0 = 0; k0 < DM; k0 += 32) {
    s16x8 af[2], bf[4];
#pragma unroll
    for (int i = 0; i < 2; i++)
      af[i] = *(const s16x8*)&Af[(h * 32 + i * 16 + l15) * ILS + k0 + quad * 8];
#pragma unroll
    for (int j = 0; j < 4; j++)
      bf[j] = *(const s16x8*)&bfb[(size_t)(ws * 64 + j * 16 + l15) * DM + k0 + quad * 8];
#pragma unroll
    for (int i = 0; i < 2; i++)
#pragma unroll
      for (int j = 0; j < 4; j++)
        acc[i][j] = __builtin_amdgcn_mfma_f32_16x16x32_bf16(af[i], bf[j], acc[i][j], 0, 0, 0);
  }
#pragma unroll
  for (int j = 0; j < 4; j++) {
    int n1 = ws * 64 + j * 16 + l15;
    float bc = bcat[n1];
#pragma unroll
    for (int i = 0; i < 2; i++)
#pragma unroll
      for (int r = 0; r < 4; r++)
        Il[(h * 32 + i * 16 + quad * 4 + r) * ILS + n1] = f2b(eluf(acc[i][j][r] + bc));
  }
  __syncthreads();

  // ---- stage B: 16 k-chunks, wave tile 32m x 64n, B-frags from L2 ----
  f32x4 acc2[2][4];
#pragma unroll
  for (int i = 0; i < 2; i++)
#pragma unroll
    for (int j = 0; j < 4; j++) acc2[i][j] = (f32x4){0.f, 0.f, 0.f, 0.f};
#pragma unroll 4
  for (int kk = 0; kk < DM; kk += 32) {
    s16x8 af[2], bf[4];
#pragma unroll
    for (int i = 0; i < 2; i++)
      af[i] = *(const s16x8*)&Il[(h * 32 + i * 16 + l15) * ILS + kk + quad * 8];
#pragma unroll
    for (int j = 0; j < 4; j++)
      bf[j] = *(const s16x8*)&wc2t[(size_t)(ws * 64 + j * 16 + l15) * DM + kk + quad * 8];
#pragma unroll
    for (int i = 0; i < 2; i++)
#pragma unroll
      for (int j = 0; j < 4; j++)
        acc2[i][j] = __builtin_amdgcn_mfma_f32_16x16x32_bf16(af[i], bf[j], acc2[i][j], 0, 0, 0);
  }

  // ---- epilogue: rl[m] = sum_n elu((acc2 + bcat2)*c)*raw ----
  float epi[8];
#pragma unroll
  for (int e = 0; e < 8; e++) epi[e] = 0.f;
#pragma unroll
  for (int j = 0; j < 4; j++) {
    int n2 = ws * 64 + j * 16 + l15;
    float b2 = bcat2[n2], cc = cbuf[(size_t)b * DM + n2], rw = raw[n2];
#pragma unroll
    for (int i = 0; i < 2; i++)
#pragma unroll
      for (int r = 0; r < 4; r++)
        epi[i * 4 + r] += eluf((acc2[i][j][r] + b2) * cc) * rw;
  }
#pragma unroll
  for (int d2 = 1; d2 < 16; d2 <<= 1)
#pragma unroll
    for (int e = 0; e < 8; e++) epi[e] += __shfl_xor(epi[e], d2, 64);
  if (l15 == 0) {
#pragma unroll
    for (int i = 0; i < 2; i++)
#pragma unroll
      for (int r = 0; r < 4; r++)
        red[(h * 32 + i * 16 + quad * 4 + r) * 8 + ws] = epi[i * 4 + r];
  }
  __syncthreads();
  if (t < 64) {
    int m = m0 + t;
    if (m < SP) {
      float s = 0.f;
#pragma unroll
      for (int q = 0; q < 8; q++) s += red[t * 8 + q];
      rl[(size_t)b * SP + m] = s;
    }
  }
}

// ---------------------------------------------------------------------------
// Per-step fold: befft[b][n][k] = bf16(mp[b][k]*Wcat[k][n] + Wcat[512+k][n])
// ---------------------------------------------------------------------------
__global__ __launch_bounds__(256) void k_prefold(
    const float* __restrict__ Wcat, const float* __restrict__ mp,
    ushort* __restrict__ Bf)
{
  const int k0 = blockIdx.x * 64, n0 = blockIdx.y * 64;
  const int bbase = blockIdx.z * 8;
  __shared__ float S1[64][68], S2[64][68];
  const int t = threadIdx.x;
#pragma unroll
  for (int i = 0; i < 4; i++) {
    int f = t + i * 256;
    int kk = f >> 4, nn2 = (f & 15) * 4;
    float4 a = *(const float4*)&Wcat[(size_t)(k0 + kk) * DM + n0 + nn2];
    float4 c = *(const float4*)&Wcat[(size_t)(DM + k0 + kk) * DM + n0 + nn2];
    *(float4*)&S1[kk][nn2] = a;
    *(float4*)&S2[kk][nn2] = c;
  }
  __syncthreads();
  const int n = t >> 2, kseg = (t & 3) * 16;
  for (int bq = 0; bq < 8; bq++) {
    const float* mpb = mp + (size_t)(bbase + bq) * DM + k0 + kseg;
    ushort* out = Bf + ((size_t)(bbase + bq) * DM + n0 + n) * DM + k0 + kseg;
#pragma unroll
    for (int g = 0; g < 4; g++) {
      ushort4 o;
      o.x = f2b(mpb[g * 4 + 0] * S1[kseg + g * 4 + 0][n] + S2[kseg + g * 4 + 0][n]);
      o.y = f2b(mpb[g * 4 + 1] * S1[kseg + g * 4 + 1][n] + S2[kseg + g * 4 + 1][n]);
      o.z = f2b(mpb[g * 4 + 2] * S1[kseg + g * 4 + 2][n] + S2[kseg + g * 4 + 2][n]);
      o.w = f2b(mpb[g * 4 + 3] * S1[kseg + g * 4 + 3][n] + S2[kseg + g * 4 + 3][n]);
      *(ushort4*)&out[g * 4] = o;
    }
  }
}

// ---------------------------------------------------------------------------
// Control unit (unchanged)
// ---------------------------------------------------------------------------
__global__ __launch_bounds__(256) void k_ctrl(
    const float* cin, const float* __restrict__ min_,
    const float* __restrict__ Wci, const float* __restrict__ bci,
    const float* __restrict__ Wu_i, const float* __restrict__ bu_i,
    const float* __restrict__ caw, const float* __restrict__ concepts,
    const float* __restrict__ Wm, const float* __restrict__ bm,
    float* cout, float* __restrict__ mpout)
{
  const int b = blockIdx.x, t = threadIdx.x;
  __shared__ float sc[512], sm[512], sq0[512], sqa[512], scl[80], red[256];
  sc[t] = cin[b * DM + t];       sc[t + 256] = cin[b * DM + t + 256];
  sm[t] = min_[b * DM + t];      sm[t + 256] = min_[b * DM + t + 256];
  __syncthreads();
#pragma unroll
  for (int h = 0; h < 2; h++) {
    int d = t + h * 256;
    float a = bci[d];
    for (int k = 0; k < 512; k++) a = fmaf(sc[k], Wci[k * DM + d], a);
    for (int k = 0; k < 512; k++) a = fmaf(sm[k], Wci[(512 + k) * DM + d], a);
    sq0[d] = tanhf(a);
    float mpa = bm[d];
    for (int k = 0; k < 512; k++) mpa = fmaf(sm[k], Wm[k * DM + d], mpa);
    mpout[b * DM + d] = mpa;
  }
  __syncthreads();
#pragma unroll
  for (int h = 0; h < 2; h++) {
    int d = t + h * 256;
    float a = bu_i[d];
    for (int k = 0; k < 512; k++) a = fmaf(sq0[k], Wu_i[k * DM + d], a);
    sqa[d] = a * caw[d];
  }
  __syncthreads();
  float myl = -INFINITY;
  if (t < 80) {
    float a = 0.f;
    for (int d = 0; d < 512; d++) a = fmaf(sqa[d], concepts[t * DM + d], a);
    scl[t] = a; myl = a;
  }
  red[t] = myl; __syncthreads();
  for (int s = 128; s > 0; s >>= 1) { if (t < s) red[t] = fmaxf(red[t], red[t + s]); __syncthreads(); }
  float mx = red[0]; __syncthreads();
  float e = 0.f;
  if (t < 80) e = expf(scl[t] - mx);
  red[t] = e; __syncthreads();
  for (int s = 128; s > 0; s >>= 1) { if (t < s) red[t] += red[t + s]; __syncthreads(); }
  float inv = 1.f / red[0]; __syncthreads();
  if (t < 80) scl[t] = e * inv;
  __syncthreads();
#pragma unroll
  for (int h = 0; h < 2; h++) {
    int d = t + h * 256;
    float a = 0.f;
    for (int l = 0; l < 80; l++) a = fmaf(scl[l], concepts[l * DM + d], a);
    cout[b * DM + d] = a;
  }
}

// ---------------------------------------------------------------------------
// Fused read softmax + info partial (unchanged)
// ---------------------------------------------------------------------------
__global__ __launch_bounds__(256) void k_softinfo(
    const float* __restrict__ rl, const ushort* __restrict__ know,
    float* __restrict__ ipart)
{
  const int b = blockIdx.x, c = blockIdx.y, t = threadIdx.x;
  __shared__ float red[256];
  float vals[7]; float vmax = -INFINITY;
#pragma unroll
  for (int q = 0; q < 7; q++) {
    int s = t + q * 256;
    float v = (s < SP) ? rl[(size_t)b * SP + s] : -INFINITY;
    vals[q] = v; vmax = fmaxf(vmax, v);
  }
  red[t] = vmax; __syncthreads();
  for (int s = 128; s > 0; s >>= 1) { if (t < s) red[t] = fmaxf(red[t], red[t + s]); __syncthreads(); }
  float mx = red[0]; __syncthreads();
  float lsum = 0.f;
#pragma unroll
  for (int q = 0; q < 7; q++) {
    int s = t + q * 256;
    lsum += (s < SP) ? expf(vals[q] - mx) : 0.f;
  }
  red[t] = lsum; __syncthreads();
  for (int s = 128; s > 0; s >>= 1) { if (t < s) red[t] += red[t + s]; __syncthreads(); }
  float inv = 1.f / red[0];

  float a0 = 0.f, a1 = 0.f;
  const ushort* kb = know + (size_t)b * SP * DM + 2 * t;
  const float* rlb = rl + (size_t)b * SP;
  for (int s = c * 196; s < (c + 1) * 196; s++) {
    float r = expf(rlb[s] - mx) * inv;
    ushort2 kv = *(const ushort2*)&kb[(size_t)s * DM];
    a0 = fmaf(r, b2f(kv.x), a0);
    a1 = fmaf(r, b2f(kv.y), a1);
  }
  ipart[((size_t)b * 8 + c) * DM + 2 * t] = a0;
  ipart[((size_t)b * 8 + c) * DM + 2 * t + 1] = a1;
}

// m_new = [m_old, info] @ Wwrite + bwrite
__global__ __launch_bounds__(256) void k_write(
    const float* __restrict__ mold, const float* __restrict__ ipart,
    const float* __restrict__ Ww, const float* __restrict__ bw,
    float* __restrict__ mnew)
{
  const int b = blockIdx.x, half = blockIdx.y, t = threadIdx.x;
  __shared__ float smo[512], sinfo[512];
  for (int k = t; k < 512; k += 256) {
    smo[k] = mold[b * DM + k];
    float s = 0.f;
    for (int c = 0; c < 8; c++) s += ipart[((size_t)b * 8 + c) * DM + k];
    sinfo[k] = s;
  }
  __syncthreads();
  int d = half * 256 + t;
  float a = bw[d];
  for (int k = 0; k < 512; k++) a = fmaf(smo[k], Ww[k * DM + d], a);
  for (int k = 0; k < 512; k++) a = fmaf(sinfo[k], Ww[(512 + k) * DM + d], a);
  mnew[b * DM + d] = a;
}

__global__ void k_init(const float* __restrict__ initc, const float* __restrict__ initm,
                       float* __restrict__ cbuf, float* __restrict__ mbuf)
{
  const int b = blockIdx.x, t = threadIdx.x;
  cbuf[b * DM + t] = initc[t];
  mbuf[b * DM + t] = initm[t];
}

__global__ void k_mpo(const float* __restrict__ m, const float* __restrict__ Wproj,
                      const float* __restrict__ bproj, const float* __restrict__ ow,
                      float* __restrict__ mw)
{
  const int b = blockIdx.x, t = threadIdx.x;
  __shared__ float smem[512];
  for (int k = t; k < 512; k += 320) smem[k] = m[b * DM + k];
  __syncthreads();
  if (t < 300) {
    float a = bproj[t];
    for (int k = 0; k < 512; k++) a = fmaf(smem[k], Wproj[k * 300 + t], a);
    mw[b * 300 + t] = a * ow[t];
  }
}

__global__ void k_logits(const float* __restrict__ mw, const float* __restrict__ labels,
                         float* __restrict__ logits)
{
  const int b = blockIdx.x, t = threadIdx.x;
  const int a = blockIdx.y * 256 + t;
  __shared__ float smw[300];
  for (int p = t; p < 300; p += 256) smw[p] = mw[b * 300 + p];
  __syncthreads();
  if (a < 1000) {
    float acc = 0.f;
    for (int p = 0; p < 300; p++) acc = fmaf(smw[p], labels[a * 300 + p], acc);
    logits[b * 1000 + a] = acc;
  }
}

__global__ void k_softmax_out(const float* __restrict__ logits, float* __restrict__ out)
{
  const int b = blockIdx.x, t = threadIdx.x;
  __shared__ float red[256];
  float v[4]; float vmax = -INFINITY;
#pragma unroll
  for (int q = 0; q < 4; q++) {
    int a = t + q * 256;
    v[q] = (a < 1000) ? logits[b * 1000 + a] : -INFINITY;
    vmax = fmaxf(vmax, v[q]);
  }
  red[t] = vmax; __syncthreads();
  for (int s = 128; s > 0; s >>= 1) { if (t < s) red[t] = fmaxf(red[t], red[t + s]); __syncthreads(); }
  float mx = red[0]; __syncthreads();
  float lsum = 0.f;
#pragma unroll
  for (int q = 0; q < 4; q++) {
    int a = t + q * 256;
    v[q] = (a < 1000) ? expf(v[q] - mx) : 0.f;
    lsum += v[q];
  }
  red[t] = lsum; __syncthreads();
  for (int s = 128; s > 0; s >>= 1) { if (t < s) red[t] += red[t + s]; __syncthreads(); }
  float inv = 1.f / red[0];
#pragma unroll
  for (int q = 0; q < 4; q++) {
    int a = t + q * 256;
    if (a < 1000) out[b * 1000 + a] = v[q] * inv;
  }
}

// ---------------------------------------------------------------------------
extern "C" void kernel_launch(void* const* d_in, const int* in_sizes, int n_in,
                              void* d_out, int out_size, void* d_ws, size_t ws_size,
                              hipStream_t stream)
{
  const float* image    = (const float*)d_in[0];
  const float* concepts = (const float*)d_in[1];
  const float* conv1_w  = (const float*)d_in[2];
  const float* conv1_b  = (const float*)d_in[3];
  const float* conv2_w  = (const float*)d_in[4];
  const float* conv2_b  = (const float*)d_in[5];
  const float* Wci      = (const float*)d_in[6];
  const float* bci      = (const float*)d_in[7];
  const float* Wu       = (const float*)d_in[8];
  const float* bu       = (const float*)d_in[9];
  const float* caw      = (const float*)d_in[10];
  const float* Wk       = (const float*)d_in[12];
  const float* bk       = (const float*)d_in[13];
  const float* Wm       = (const float*)d_in[14];
  const float* bm       = (const float*)d_in[15];
  const float* Wcat     = (const float*)d_in[16];
  const float* bcat     = (const float*)d_in[17];
  const float* Wcat2    = (const float*)d_in[18];
  const float* bcat2    = (const float*)d_in[19];
  const float* raw      = (const float*)d_in[20];
  const float* Wwrite   = (const float*)d_in[22];
  const float* bwrite   = (const float*)d_in[23];
  const float* initc    = (const float*)d_in[24];
  const float* initm    = (const float*)d_in[25];
  const float* Wproj    = (const float*)d_in[26];
  const float* bproj    = (const float*)d_in[27];
  const float* oaw      = (const float*)d_in[28];
  const float* labels   = (const float*)d_in[30];

  char* ws = (char*)d_ws;
  const size_t OFF_KNOW = 0;
  const size_t OFF_XPAD = 51380224;
  const size_t SZ_XPAD  = 83951616;
  const size_t OFF_W    = OFF_XPAD + SZ_XPAD;
  const size_t OFF_WKT  = OFF_W + 14155776;
  const size_t OFF_WC2T = OFF_WKT + 524288;
  size_t off = OFF_WC2T + 524288;
  auto allocB = [&](size_t bytes) {
    void* p = ws + off; off += (bytes + 255) & ~(size_t)255; return p;
  };
  ushort* know   = (ushort*)(ws + OFF_KNOW);
  ushort* imgpad = (ushort*)(ws + OFF_KNOW);                 // stem only
  ushort* xpad1  = (ushort*)(ws + OFF_XPAD);                 // stem only
  ushort* kproj  = (ushort*)(ws + OFF_XPAD);                 // loop
  ushort* befft  = (ushort*)(ws + OFF_XPAD + 51380224);      // loop, 16.78MB
  float*  rl     = (float*) (ws + OFF_XPAD + 68157440);      // loop, 0.2MB
  ushort* w1b    = (ushort*)(ws + OFF_W);
  ushort* w2b    = (ushort*)(ws + OFF_W);
  ushort* wkt    = (ushort*)(ws + OFF_WKT);
  ushort* wc2t   = (ushort*)(ws + OFF_WC2T);
  float* ipart  = (float*)allocB((size_t)BATCH * 8 * DM * 4);
  float* cbuf   = (float*)allocB(BATCH * DM * 4);
  float* mbufA  = (float*)allocB(BATCH * DM * 4);
  float* mbufB  = (float*)allocB(BATCH * DM * 4);
  float* mp     = (float*)allocB(BATCH * DM * 4);
  float* mw     = (float*)allocB(BATCH * 300 * 4);
  float* logits = (float*)allocB(BATCH * 1000 * 4);
  if (off > ws_size) return;  // graceful fail

  const int FUSED_LDS = 64 * ILS * 2 * 2 + 64 * 8 * 4;  // 135,168 B
  hipFuncSetAttribute((const void*)k_fused12,
                      hipFuncAttributeMaxDynamicSharedMemorySize, FUSED_LDS);

  // --- stem ---
  k_zero<<<4096, 256, 0, stream>>>((uint4*)imgpad, 2625536L);
  k_zero<<<4096, 256, 0, stream>>>((uint4*)xpad1, 5246976L);
  k_padimg<<<BATCH * SP, 256, 0, stream>>>(image, imgpad);
  k_cvtw<256><<<13824, 256, 0, stream>>>(conv1_w, w1b);
  k_cvtT<<<1024, 256, 0, stream>>>(Wk, wkt);
  k_cvtT<<<1024, 256, 0, stream>>>(Wcat2, wc2t);
  k_convm<256, 1><<<dim3(16, 4, 32), 256, 0, stream>>>(w1b, imgpad, conv1_b, xpad1);
  k_cvtw<512><<<27648, 256, 0, stream>>>(conv2_w, w2b);
  k_convm<512, 0><<<dim3(16, 4, 32), 256, 0, stream>>>(w2b, xpad1, conv2_b, know);
  k_gemmm<<<dim3(13, 4, 32), 256, 0, stream>>>(know, wkt, bk, kproj);
  k_init<<<BATCH, DM, 0, stream>>>(initc, initm, cbuf, mbufA);

  float* mc = mbufA; float* mn = mbufB;
  for (int i = 0; i < NSTEP; i++) {
    k_ctrl<<<BATCH, 256, 0, stream>>>(cbuf, mc, Wci, bci,
                                      Wu + (size_t)i * DM * DM, bu + i * DM,
                                      caw, concepts, Wm, bm, cbuf, mp);
    k_prefold<<<dim3(8, 8, 4), 256, 0, stream>>>(Wcat, mp, befft);
    k_fused12<<<dim3(25, 32), 1024, FUSED_LDS, stream>>>(
        kproj, befft, wc2t, bcat, bcat2, cbuf, raw, rl);
    k_softinfo<<<dim3(BATCH, 8), 256, 0, stream>>>(rl, know, ipart);
    k_write<<<dim3(BATCH, 2), 256, 0, stream>>>(mc, ipart, Wwrite, bwrite, mn);
    float* tswap = mc; mc = mn; mn = tswap;
  }

  k_mpo<<<BATCH, 320, 0, stream>>>(mc, Wproj, bproj, oaw, mw);
  k_logits<<<dim3(BATCH, 4), 256, 0, stream>>>(mw, labels, logits);
  k_softmax_out<<<BATCH, 256, 0, stream>>>(logits, (float*)d_out);

  (void)in_sizes; (void)n_in; (void)out_size;
}

// Round 11
// 7332.096 us; speedup vs baseline: 1.1298x; 1.1298x over previous
//
#include <hip/hip_runtime.h>
#include <math.h>

#define DM    512
#define SP    1568   // 8*14*14
#define BATCH 32
#define NSTEP 12
#define CPAD  2560   // padded per-batch spatial rows (10*16*16)
#define LDT   40     // kproj-GEMM LDS row stride (bf16)
#define LDT2  72     // conv BK=64 LDS row stride (bf16)
#define ILS   520    // fused kernel LDS row stride (bf16)

typedef short s16x8 __attribute__((ext_vector_type(8)));
typedef float f32x4 __attribute__((ext_vector_type(4)));

__device__ __forceinline__ float eluf(float x) { return x > 0.f ? x : expf(x) - 1.f; }
__device__ __forceinline__ float b2f(ushort u) {
  union { float f; unsigned i; } v; v.i = ((unsigned)u) << 16; return v.f;
}
__device__ __forceinline__ ushort f2b(float f) {
  union { float f; unsigned i; } v; v.f = f;
  unsigned r = (v.i + 0x7FFFu + ((v.i >> 16) & 1u)) >> 16;
  return (ushort)r;
}

// ---------------------------------------------------------------------------
__global__ void k_zero(uint4* __restrict__ p, long n16) {
  long stride = (long)gridDim.x * blockDim.x;
  for (long i = (long)blockIdx.x * blockDim.x + threadIdx.x; i < n16; i += stride)
    p[i] = make_uint4(0, 0, 0, 0);
}

// image [32][256][1568] fp32 -> NHWC padded bf16 [b][2560][256] (interior only)
__global__ void k_padimg(const float* __restrict__ img, ushort* __restrict__ xp) {
  int blk = blockIdx.x;                 // 32*1568
  int b = blk / SP, s = blk - b * SP;
  int ci = threadIdx.x;                 // 256
  int z = s / 196, r = s - z * 196, y = r / 14, x = r - y * 14;
  int p = (z + 1) * 256 + (y + 1) * 16 + (x + 1);
  xp[((size_t)b * CPAD + p) * 256 + ci] = f2b(img[((size_t)b * 256 + ci) * SP + s]);
}

// conv weights [co][ci][27] fp32 -> tap-major bf16 [co][tap*CIN+ci]
template <int CIN>
__global__ void k_cvtw(const float* __restrict__ w, ushort* __restrict__ o) {
  int idx = blockIdx.x * 256 + threadIdx.x;   // < 512*27*CIN
  const int KK = 27 * CIN;
  int co = idx / KK; int rem = idx - co * KK;
  int tap = rem / CIN; int ci = rem - tap * CIN;
  o[idx] = f2b(w[((size_t)co * CIN + ci) * 27 + tap]);
}

// [512][512] fp32 -> transposed bf16 [n][k]
__global__ void k_cvtT(const float* __restrict__ w, ushort* __restrict__ o) {
  int idx = blockIdx.x * 256 + threadIdx.x;   // < 512*512
  int n = idx >> 9, k = idx & 511;
  o[idx] = f2b(w[(size_t)k * 512 + n]);
}

// ---------------------------------------------------------------------------
// MFMA conv3d, NHWC activations, BK=64 (unchanged)
// ---------------------------------------------------------------------------
template <int CIN, int ISCONV1>
__global__ __launch_bounds__(256) void k_convm(
    const ushort* __restrict__ W, const ushort* __restrict__ Xp,
    const float* __restrict__ bias, ushort* __restrict__ Y)
{
  const int KK = CIN * 27;
  const int b  = blockIdx.z;
  const int n0 = blockIdx.x * 128;
  const int m0 = blockIdx.y * 128;
  __shared__ __align__(16) ushort As[128 * LDT2];
  __shared__ __align__(16) ushort Bs[128 * LDT2];
  const int t = threadIdx.x;
  const int lane = t & 63, wid = t >> 6;
  const int wm = (wid >> 1) * 64, wn = (wid & 1) * 64;
  const int l15 = lane & 15, quad = lane >> 4;
  f32x4 acc[4][4];
#pragma unroll
  for (int i = 0; i < 4; i++)
#pragma unroll
    for (int j = 0; j < 4; j++) acc[i][j] = (f32x4){0.f, 0.f, 0.f, 0.f};

  for (int k0 = 0; k0 < KK; k0 += 64) {
#pragma unroll
    for (int i = 0; i < 4; i++) {          // A tile: 128co x 64k
      int f = t + i * 256;
      int row = f >> 3, ko = (f & 7) * 8;
      uint4 v = *(const uint4*)&W[(size_t)(m0 + row) * KK + k0 + ko];
      *(uint4*)&As[row * LDT2 + ko] = v;
    }
    {                                       // B tile: fixed tap, NHWC, 64 ci
      int tap = k0 / CIN, ci0 = k0 - tap * CIN;
      int dz = tap / 9, rr = tap - dz * 9, dy = rr / 3, dx = rr - dy * 3;
      int tofs = dz * 256 + dy * 16 + dx;
      const ushort* src = Xp + ((size_t)b * CPAD + tofs + n0) * CIN + ci0;
#pragma unroll
      for (int i = 0; i < 4; i++) {
        int f = t + i * 256;
        int row = f >> 3, ko = (f & 7) * 8;
        uint4 v = *(const uint4*)&src[(size_t)row * CIN + ko];
        *(uint4*)&Bs[row * LDT2 + ko] = v;
      }
    }
    __syncthreads();
#pragma unroll
    for (int sub = 0; sub < 2; sub++) {
      s16x8 af[4], bfr[4];
#pragma unroll
      for (int i = 0; i < 4; i++)
        af[i] = *(const s16x8*)&As[(wm + i * 16 + l15) * LDT2 + sub * 32 + quad * 8];
#pragma unroll
      for (int j = 0; j < 4; j++)
        bfr[j] = *(const s16x8*)&Bs[(wn + j * 16 + l15) * LDT2 + sub * 32 + quad * 8];
#pragma unroll
      for (int i = 0; i < 4; i++)
#pragma unroll
        for (int j = 0; j < 4; j++)
          acc[i][j] = __builtin_amdgcn_mfma_f32_16x16x32_bf16(af[i], bfr[j], acc[i][j], 0, 0, 0);
    }
    __syncthreads();
  }

#pragma unroll
  for (int i = 0; i < 4; i++) {
    int cob = m0 + wm + i * 16 + quad * 4;
    float4 bb = *(const float4*)&bias[cob];
#pragma unroll
    for (int j = 0; j < 4; j++) {
      int n = n0 + wn + j * 16 + l15;
      int z = n >> 8, y = (n >> 4) & 15, x = n & 15;
      if (y < 14 && x < 14) {
        ushort4 o;
        o.x = f2b(eluf(acc[i][j][0] + bb.x));
        o.y = f2b(eluf(acc[i][j][1] + bb.y));
        o.z = f2b(eluf(acc[i][j][2] + bb.z));
        o.w = f2b(eluf(acc[i][j][3] + bb.w));
        if (ISCONV1) {
          *(ushort4*)&Y[((size_t)b * CPAD + n + 273) * 512 + cob] = o;
        } else {
          int s = z * 196 + y * 14 + x;
          *(ushort4*)&Y[((size_t)b * SP + s) * DM + cob] = o;
        }
      }
    }
  }
}

// ---------------------------------------------------------------------------
// MFMA GEMM: kproj = know @ WkT + bk (unchanged)
// ---------------------------------------------------------------------------
__global__ __launch_bounds__(256) void k_gemmm(
    const ushort* __restrict__ A0, const ushort* __restrict__ Bt,
    const float* __restrict__ bias, ushort* __restrict__ Cv)
{
  const int bq = blockIdx.z;
  const int m0 = blockIdx.x * 128;
  const int n0 = blockIdx.y * 128;
  const ushort* A = A0 + (size_t)bq * SP * DM;
  __shared__ __align__(16) ushort As[128 * LDT];
  __shared__ __align__(16) ushort Bs[128 * LDT];
  const int t = threadIdx.x;
  const int lane = t & 63, wid = t >> 6;
  const int wm = (wid >> 1) * 64, wn = (wid & 1) * 64;
  const int l15 = lane & 15, quad = lane >> 4;
  f32x4 acc[4][4];
#pragma unroll
  for (int i = 0; i < 4; i++)
#pragma unroll
    for (int j = 0; j < 4; j++) acc[i][j] = (f32x4){0.f, 0.f, 0.f, 0.f};

  for (int k0 = 0; k0 < DM; k0 += 32) {
#pragma unroll
    for (int i = 0; i < 2; i++) {
      int f = t + i * 256;
      int row = f >> 2, ko = (f & 3) * 8;
      int mg = m0 + row;
      uint4 v = make_uint4(0, 0, 0, 0);
      if (mg < SP) v = *(const uint4*)&A[(size_t)mg * DM + k0 + ko];
      *(uint4*)&As[row * LDT + ko] = v;
      uint4 w = *(const uint4*)&Bt[(size_t)(n0 + row) * DM + k0 + ko];
      *(uint4*)&Bs[row * LDT + ko] = w;
    }
    __syncthreads();
    s16x8 af[4], bfr[4];
#pragma unroll
    for (int i = 0; i < 4; i++)
      af[i] = *(const s16x8*)&As[(wm + i * 16 + l15) * LDT + quad * 8];
#pragma unroll
    for (int j = 0; j < 4; j++)
      bfr[j] = *(const s16x8*)&Bs[(wn + j * 16 + l15) * LDT + quad * 8];
#pragma unroll
    for (int i = 0; i < 4; i++)
#pragma unroll
      for (int j = 0; j < 4; j++)
        acc[i][j] = __builtin_amdgcn_mfma_f32_16x16x32_bf16(af[i], bfr[j], acc[i][j], 0, 0, 0);
    __syncthreads();
  }

  ushort* C = Cv + (size_t)bq * SP * DM;
#pragma unroll
  for (int j = 0; j < 4; j++) {
    int n = n0 + wn + j * 16 + l15;
    float bb = bias[n];
#pragma unroll
    for (int i = 0; i < 4; i++) {
      int mb = m0 + wm + i * 16 + quad * 4;
#pragma unroll
      for (int r = 0; r < 4; r++) {
        int m = mb + r;
        if (m < SP) C[(size_t)m * DM + n] = f2b(acc[i][j][r] + bb);
      }
    }
  }
}

// ---------------------------------------------------------------------------
// Fused ReadUnit GEMM pair v7 — v4 structure with ALIASED LDS:
// one 64x520 buffer holds Af (kproj tile) during stage A, then is overwritten
// with Il (inter1) for stage B. Stage-A accumulators for BOTH strips are kept
// in registers across the alias barrier. LDS 70.7 KB -> 2 blocks/CU
// (8 waves/SIMD vs v4's 4) so barrier drains overlap across blocks (m114).
// Grid (25, 32), 1024 threads (16 waves), 3 barriers.
// ---------------------------------------------------------------------------
__global__ __launch_bounds__(1024, 8) void k_fused12(
    const ushort* __restrict__ kproj, const ushort* __restrict__ befft,
    const ushort* __restrict__ wc2t, const float* __restrict__ bcat,
    const float* __restrict__ bcat2, const float* __restrict__ cbuf,
    const float* __restrict__ raw, float* __restrict__ rl)
{
  extern __shared__ __align__(16) char smem[];
  ushort* Buf = (ushort*)smem;                 // 64*520: Af, then Il (aliased)
  float*  red = (float*)(Buf + 64 * ILS);      // 64*16

  const int b  = blockIdx.y;
  const int m0 = blockIdx.x * 64;
  const int t  = threadIdx.x;
  const int lane = t & 63, w = t >> 6;         // 16 waves
  const int l15 = lane & 15, quad = lane >> 4;

  // cooperative load of kproj 64x512 tile into Buf (Af phase)
  const ushort* kpb = kproj + (size_t)b * SP * DM;
#pragma unroll
  for (int i = 0; i < 4; i++) {
    int f = t + i * 1024;                      // 4096 uint4 chunks
    int row = f >> 6, ch = (f & 63) * 8;
    int mg = m0 + row;
    uint4 v = make_uint4(0, 0, 0, 0);
    if (mg < SP) v = *(const uint4*)&kpb[(size_t)mg * DM + ch];
    *(uint4*)&Buf[row * ILS + ch] = v;
  }
  __syncthreads();

  // ---- stage A: 2 strips x 16 k-chunks, acc for both strips in regs ----
  const ushort* bfb = befft + (size_t)b * DM * DM;
  f32x4 acc[2][4];
#pragma unroll
  for (int p = 0; p < 2; p++)
#pragma unroll
    for (int i = 0; i < 4; i++) acc[p][i] = (f32x4){0.f, 0.f, 0.f, 0.f};
#pragma unroll 1
  for (int p = 0; p < 2; p++) {
    const int n1 = p * 256 + w * 16 + l15;
#pragma unroll 4
    for (int k0 = 0; k0 < DM; k0 += 32) {
      s16x8 bf = *(const s16x8*)&bfb[(size_t)n1 * DM + k0 + quad * 8];
#pragma unroll
      for (int i = 0; i < 4; i++) {
        s16x8 af = *(const s16x8*)&Buf[(i * 16 + l15) * ILS + k0 + quad * 8];
        acc[p][i] = __builtin_amdgcn_mfma_f32_16x16x32_bf16(af, bf, acc[p][i], 0, 0, 0);
      }
    }
  }
  __syncthreads();   // all Af reads complete — safe to overwrite with Il

#pragma unroll
  for (int p = 0; p < 2; p++) {
    int n1 = p * 256 + w * 16 + l15;
    float bc = bcat[n1];
#pragma unroll
    for (int i = 0; i < 4; i++)
#pragma unroll
      for (int r = 0; r < 4; r++)
        Buf[(i * 16 + quad * 4 + r) * ILS + n1] = f2b(eluf(acc[p][i][r] + bc));
  }
  __syncthreads();

  // ---- stage B: 16 k-chunks; each wave covers n2 = w*32 .. w*32+31 ----
  f32x4 acc2[4][2];
#pragma unroll
  for (int i = 0; i < 4; i++)
#pragma unroll
    for (int j = 0; j < 2; j++) acc2[i][j] = (f32x4){0.f, 0.f, 0.f, 0.f};
#pragma unroll 4
  for (int kk = 0; kk < DM; kk += 32) {
    s16x8 af[4], bf[2];
#pragma unroll
    for (int i = 0; i < 4; i++)
      af[i] = *(const s16x8*)&Buf[(i * 16 + l15) * ILS + kk + quad * 8];
#pragma unroll
    for (int j = 0; j < 2; j++)
      bf[j] = *(const s16x8*)&wc2t[(size_t)(w * 32 + j * 16 + l15) * DM + kk + quad * 8];
#pragma unroll
    for (int i = 0; i < 4; i++)
#pragma unroll
      for (int j = 0; j < 2; j++)
        acc2[i][j] = __builtin_amdgcn_mfma_f32_16x16x32_bf16(af[i], bf[j], acc2[i][j], 0, 0, 0);
  }

  // ---- epilogue: rl[m] = sum_n elu((acc2 + bcat2)*c)*raw ----
  float epi[16];
#pragma unroll
  for (int e = 0; e < 16; e++) epi[e] = 0.f;
#pragma unroll
  for (int j = 0; j < 2; j++) {
    int n2 = w * 32 + j * 16 + l15;
    float b2 = bcat2[n2], cc = cbuf[(size_t)b * DM + n2], rw = raw[n2];
#pragma unroll
    for (int i = 0; i < 4; i++)
#pragma unroll
      for (int r = 0; r < 4; r++)
        epi[i * 4 + r] += eluf((acc2[i][j][r] + b2) * cc) * rw;
  }
#pragma unroll
  for (int d2 = 1; d2 < 16; d2 <<= 1)
#pragma unroll
    for (int e = 0; e < 16; e++) epi[e] += __shfl_xor(epi[e], d2, 64);
  if (l15 == 0) {
#pragma unroll
    for (int i = 0; i < 4; i++)
#pragma unroll
      for (int r = 0; r < 4; r++)
        red[(i * 16 + quad * 4 + r) * 16 + w] = epi[i * 4 + r];
  }
  __syncthreads();
  if (t < 64) {
    int m = m0 + t;
    if (m < SP) {
      float s = 0.f;
#pragma unroll
      for (int q = 0; q < 16; q++) s += red[t * 16 + q];
      rl[(size_t)b * SP + m] = s;
    }
  }
}

// ---------------------------------------------------------------------------
// Per-step fold: befft[b][n][k] = bf16(mp[b][k]*Wcat[k][n] + Wcat[512+k][n])
// ---------------------------------------------------------------------------
__global__ __launch_bounds__(256) void k_prefold(
    const float* __restrict__ Wcat, const float* __restrict__ mp,
    ushort* __restrict__ Bf)
{
  const int k0 = blockIdx.x * 64, n0 = blockIdx.y * 64;
  const int bbase = blockIdx.z * 8;
  __shared__ float S1[64][68], S2[64][68];
  const int t = threadIdx.x;
#pragma unroll
  for (int i = 0; i < 4; i++) {
    int f = t + i * 256;
    int kk = f >> 4, nn2 = (f & 15) * 4;
    float4 a = *(const float4*)&Wcat[(size_t)(k0 + kk) * DM + n0 + nn2];
    float4 c = *(const float4*)&Wcat[(size_t)(DM + k0 + kk) * DM + n0 + nn2];
    *(float4*)&S1[kk][nn2] = a;
    *(float4*)&S2[kk][nn2] = c;
  }
  __syncthreads();
  const int n = t >> 2, kseg = (t & 3) * 16;
  for (int bq = 0; bq < 8; bq++) {
    const float* mpb = mp + (size_t)(bbase + bq) * DM + k0 + kseg;
    ushort* out = Bf + ((size_t)(bbase + bq) * DM + n0 + n) * DM + k0 + kseg;
#pragma unroll
    for (int g = 0; g < 4; g++) {
      ushort4 o;
      o.x = f2b(mpb[g * 4 + 0] * S1[kseg + g * 4 + 0][n] + S2[kseg + g * 4 + 0][n]);
      o.y = f2b(mpb[g * 4 + 1] * S1[kseg + g * 4 + 1][n] + S2[kseg + g * 4 + 1][n]);
      o.z = f2b(mpb[g * 4 + 2] * S1[kseg + g * 4 + 2][n] + S2[kseg + g * 4 + 2][n]);
      o.w = f2b(mpb[g * 4 + 3] * S1[kseg + g * 4 + 3][n] + S2[kseg + g * 4 + 3][n]);
      *(ushort4*)&out[g * 4] = o;
    }
  }
}

// ---------------------------------------------------------------------------
// Control unit (unchanged)
// ---------------------------------------------------------------------------
__global__ __launch_bounds__(256) void k_ctrl(
    const float* cin, const float* __restrict__ min_,
    const float* __restrict__ Wci, const float* __restrict__ bci,
    const float* __restrict__ Wu_i, const float* __restrict__ bu_i,
    const float* __restrict__ caw, const float* __restrict__ concepts,
    const float* __restrict__ Wm, const float* __restrict__ bm,
    float* cout, float* __restrict__ mpout)
{
  const int b = blockIdx.x, t = threadIdx.x;
  __shared__ float sc[512], sm[512], sq0[512], sqa[512], scl[80], red[256];
  sc[t] = cin[b * DM + t];       sc[t + 256] = cin[b * DM + t + 256];
  sm[t] = min_[b * DM + t];      sm[t + 256] = min_[b * DM + t + 256];
  __syncthreads();
#pragma unroll
  for (int h = 0; h < 2; h++) {
    int d = t + h * 256;
    float a = bci[d];
    for (int k = 0; k < 512; k++) a = fmaf(sc[k], Wci[k * DM + d], a);
    for (int k = 0; k < 512; k++) a = fmaf(sm[k], Wci[(512 + k) * DM + d], a);
    sq0[d] = tanhf(a);
    float mpa = bm[d];
    for (int k = 0; k < 512; k++) mpa = fmaf(sm[k], Wm[k * DM + d], mpa);
    mpout[b * DM + d] = mpa;
  }
  __syncthreads();
#pragma unroll
  for (int h = 0; h < 2; h++) {
    int d = t + h * 256;
    float a = bu_i[d];
    for (int k = 0; k < 512; k++) a = fmaf(sq0[k], Wu_i[k * DM + d], a);
    sqa[d] = a * caw[d];
  }
  __syncthreads();
  float myl = -INFINITY;
  if (t < 80) {
    float a = 0.f;
    for (int d = 0; d < 512; d++) a = fmaf(sqa[d], concepts[t * DM + d], a);
    scl[t] = a; myl = a;
  }
  red[t] = myl; __syncthreads();
  for (int s = 128; s > 0; s >>= 1) { if (t < s) red[t] = fmaxf(red[t], red[t + s]); __syncthreads(); }
  float mx = red[0]; __syncthreads();
  float e = 0.f;
  if (t < 80) e = expf(scl[t] - mx);
  red[t] = e; __syncthreads();
  for (int s = 128; s > 0; s >>= 1) { if (t < s) red[t] += red[t + s]; __syncthreads(); }
  float inv = 1.f / red[0]; __syncthreads();
  if (t < 80) scl[t] = e * inv;
  __syncthreads();
#pragma unroll
  for (int h = 0; h < 2; h++) {
    int d = t + h * 256;
    float a = 0.f;
    for (int l = 0; l < 80; l++) a = fmaf(scl[l], concepts[l * DM + d], a);
    cout[b * DM + d] = a;
  }
}

// ---------------------------------------------------------------------------
// Fused read softmax + info partial (unchanged)
// ---------------------------------------------------------------------------
__global__ __launch_bounds__(256) void k_softinfo(
    const float* __restrict__ rl, const ushort* __restrict__ know,
    float* __restrict__ ipart)
{
  const int b = blockIdx.x, c = blockIdx.y, t = threadIdx.x;
  __shared__ float red[256];
  float vals[7]; float vmax = -INFINITY;
#pragma unroll
  for (int q = 0; q < 7; q++) {
    int s = t + q * 256;
    float v = (s < SP) ? rl[(size_t)b * SP + s] : -INFINITY;
    vals[q] = v; vmax = fmaxf(vmax, v);
  }
  red[t] = vmax; __syncthreads();
  for (int s = 128; s > 0; s >>= 1) { if (t < s) red[t] = fmaxf(red[t], red[t + s]); __syncthreads(); }
  float mx = red[0]; __syncthreads();
  float lsum = 0.f;
#pragma unroll
  for (int q = 0; q < 7; q++) {
    int s = t + q * 256;
    lsum += (s < SP) ? expf(vals[q] - mx) : 0.f;
  }
  red[t] = lsum; __syncthreads();
  for (int s = 128; s > 0; s >>= 1) { if (t < s) red[t] += red[t + s]; __syncthreads(); }
  float inv = 1.f / red[0];

  float a0 = 0.f, a1 = 0.f;
  const ushort* kb = know + (size_t)b * SP * DM + 2 * t;
  const float* rlb = rl + (size_t)b * SP;
  for (int s = c * 196; s < (c + 1) * 196; s++) {
    float r = expf(rlb[s] - mx) * inv;
    ushort2 kv = *(const ushort2*)&kb[(size_t)s * DM];
    a0 = fmaf(r, b2f(kv.x), a0);
    a1 = fmaf(r, b2f(kv.y), a1);
  }
  ipart[((size_t)b * 8 + c) * DM + 2 * t] = a0;
  ipart[((size_t)b * 8 + c) * DM + 2 * t + 1] = a1;
}

// m_new = [m_old, info] @ Wwrite + bwrite
__global__ __launch_bounds__(256) void k_write(
    const float* __restrict__ mold, const float* __restrict__ ipart,
    const float* __restrict__ Ww, const float* __restrict__ bw,
    float* __restrict__ mnew)
{
  const int b = blockIdx.x, half = blockIdx.y, t = threadIdx.x;
  __shared__ float smo[512], sinfo[512];
  for (int k = t; k < 512; k += 256) {
    smo[k] = mold[b * DM + k];
    float s = 0.f;
    for (int c = 0; c < 8; c++) s += ipart[((size_t)b * 8 + c) * DM + k];
    sinfo[k] = s;
  }
  __syncthreads();
  int d = half * 256 + t;
  float a = bw[d];
  for (int k = 0; k < 512; k++) a = fmaf(smo[k], Ww[k * DM + d], a);
  for (int k = 0; k < 512; k++) a = fmaf(sinfo[k], Ww[(512 + k) * DM + d], a);
  mnew[b * DM + d] = a;
}

__global__ void k_init(const float* __restrict__ initc, const float* __restrict__ initm,
                       float* __restrict__ cbuf, float* __restrict__ mbuf)
{
  const int b = blockIdx.x, t = threadIdx.x;
  cbuf[b * DM + t] = initc[t];
  mbuf[b * DM + t] = initm[t];
}

__global__ void k_mpo(const float* __restrict__ m, const float* __restrict__ Wproj,
                      const float* __restrict__ bproj, const float* __restrict__ ow,
                      float* __restrict__ mw)
{
  const int b = blockIdx.x, t = threadIdx.x;
  __shared__ float smem[512];
  for (int k = t; k < 512; k += 320) smem[k] = m[b * DM + k];
  __syncthreads();
  if (t < 300) {
    float a = bproj[t];
    for (int k = 0; k < 512; k++) a = fmaf(smem[k], Wproj[k * 300 + t], a);
    mw[b * 300 + t] = a * ow[t];
  }
}

__global__ void k_logits(const float* __restrict__ mw, const float* __restrict__ labels,
                         float* __restrict__ logits)
{
  const int b = blockIdx.x, t = threadIdx.x;
  const int a = blockIdx.y * 256 + t;
  __shared__ float smw[300];
  for (int p = t; p < 300; p += 256) smw[p] = mw[b * 300 + p];
  __syncthreads();
  if (a < 1000) {
    float acc = 0.f;
    for (int p = 0; p < 300; p++) acc = fmaf(smw[p], labels[a * 300 + p], acc);
    logits[b * 1000 + a] = acc;
  }
}

__global__ void k_softmax_out(const float* __restrict__ logits, float* __restrict__ out)
{
  const int b = blockIdx.x, t = threadIdx.x;
  __shared__ float red[256];
  float v[4]; float vmax = -INFINITY;
#pragma unroll
  for (int q = 0; q < 4; q++) {
    int a = t + q * 256;
    v[q] = (a < 1000) ? logits[b * 1000 + a] : -INFINITY;
    vmax = fmaxf(vmax, v[q]);
  }
  red[t] = vmax; __syncthreads();
  for (int s = 128; s > 0; s >>= 1) { if (t < s) red[t] = fmaxf(red[t], red[t + s]); __syncthreads(); }
  float mx = red[0]; __syncthreads();
  float lsum = 0.f;
#pragma unroll
  for (int q = 0; q < 4; q++) {
    int a = t + q * 256;
    v[q] = (a < 1000) ? expf(v[q] - mx) : 0.f;
    lsum += v[q];
  }
  red[t] = lsum; __syncthreads();
  for (int s = 128; s > 0; s >>= 1) { if (t < s) red[t] += red[t + s]; __syncthreads(); }
  float inv = 1.f / red[0];
#pragma unroll
  for (int q = 0; q < 4; q++) {
    int a = t + q * 256;
    if (a < 1000) out[b * 1000 + a] = v[q] * inv;
  }
}

// ---------------------------------------------------------------------------
extern "C" void kernel_launch(void* const* d_in, const int* in_sizes, int n_in,
                              void* d_out, int out_size, void* d_ws, size_t ws_size,
                              hipStream_t stream)
{
  const float* image    = (const float*)d_in[0];
  const float* concepts = (const float*)d_in[1];
  const float* conv1_w  = (const float*)d_in[2];
  const float* conv1_b  = (const float*)d_in[3];
  const float* conv2_w  = (const float*)d_in[4];
  const float* conv2_b  = (const float*)d_in[5];
  const float* Wci      = (const float*)d_in[6];
  const float* bci      = (const float*)d_in[7];
  const float* Wu       = (const float*)d_in[8];
  const float* bu       = (const float*)d_in[9];
  const float* caw      = (const float*)d_in[10];
  const float* Wk       = (const float*)d_in[12];
  const float* bk       = (const float*)d_in[13];
  const float* Wm       = (const float*)d_in[14];
  const float* bm       = (const float*)d_in[15];
  const float* Wcat     = (const float*)d_in[16];
  const float* bcat     = (const float*)d_in[17];
  const float* Wcat2    = (const float*)d_in[18];
  const float* bcat2    = (const float*)d_in[19];
  const float* raw      = (const float*)d_in[20];
  const float* Wwrite   = (const float*)d_in[22];
  const float* bwrite   = (const float*)d_in[23];
  const float* initc    = (const float*)d_in[24];
  const float* initm    = (const float*)d_in[25];
  const float* Wproj    = (const float*)d_in[26];
  const float* bproj    = (const float*)d_in[27];
  const float* oaw      = (const float*)d_in[28];
  const float* labels   = (const float*)d_in[30];

  char* ws = (char*)d_ws;
  const size_t OFF_KNOW = 0;
  const size_t OFF_XPAD = 51380224;
  const size_t SZ_XPAD  = 83951616;
  const size_t OFF_W    = OFF_XPAD + SZ_XPAD;
  const size_t OFF_WKT  = OFF_W + 14155776;
  const size_t OFF_WC2T = OFF_WKT + 524288;
  size_t off = OFF_WC2T + 524288;
  auto allocB = [&](size_t bytes) {
    void* p = ws + off; off += (bytes + 255) & ~(size_t)255; return p;
  };
  ushort* know   = (ushort*)(ws + OFF_KNOW);
  ushort* imgpad = (ushort*)(ws + OFF_KNOW);                 // stem only
  ushort* xpad1  = (ushort*)(ws + OFF_XPAD);                 // stem only
  ushort* kproj  = (ushort*)(ws + OFF_XPAD);                 // loop
  ushort* befft  = (ushort*)(ws + OFF_XPAD + 51380224);      // loop, 16.78MB
  float*  rl     = (float*) (ws + OFF_XPAD + 68157440);      // loop, 0.2MB
  ushort* w1b    = (ushort*)(ws + OFF_W);
  ushort* w2b    = (ushort*)(ws + OFF_W);
  ushort* wkt    = (ushort*)(ws + OFF_WKT);
  ushort* wc2t   = (ushort*)(ws + OFF_WC2T);
  float* ipart  = (float*)allocB((size_t)BATCH * 8 * DM * 4);
  float* cbuf   = (float*)allocB(BATCH * DM * 4);
  float* mbufA  = (float*)allocB(BATCH * DM * 4);
  float* mbufB  = (float*)allocB(BATCH * DM * 4);
  float* mp     = (float*)allocB(BATCH * DM * 4);
  float* mw     = (float*)allocB(BATCH * 300 * 4);
  float* logits = (float*)allocB(BATCH * 1000 * 4);
  if (off > ws_size) return;  // graceful fail

  const int FUSED_LDS = 64 * ILS * 2 + 64 * 16 * 4;  // 70,656 B -> 2 blocks/CU
  hipFuncSetAttribute((const void*)k_fused12,
                      hipFuncAttributeMaxDynamicSharedMemorySize, FUSED_LDS);

  // --- stem ---
  k_zero<<<4096, 256, 0, stream>>>((uint4*)imgpad, 2625536L);
  k_zero<<<4096, 256, 0, stream>>>((uint4*)xpad1, 5246976L);
  k_padimg<<<BATCH * SP, 256, 0, stream>>>(image, imgpad);
  k_cvtw<256><<<13824, 256, 0, stream>>>(conv1_w, w1b);
  k_cvtT<<<1024, 256, 0, stream>>>(Wk, wkt);
  k_cvtT<<<1024, 256, 0, stream>>>(Wcat2, wc2t);
  k_convm<256, 1><<<dim3(16, 4, 32), 256, 0, stream>>>(w1b, imgpad, conv1_b, xpad1);
  k_cvtw<512><<<27648, 256, 0, stream>>>(conv2_w, w2b);
  k_convm<512, 0><<<dim3(16, 4, 32), 256, 0, stream>>>(w2b, xpad1, conv2_b, know);
  k_gemmm<<<dim3(13, 4, 32), 256, 0, stream>>>(know, wkt, bk, kproj);
  k_init<<<BATCH, DM, 0, stream>>>(initc, initm, cbuf, mbufA);

  float* mc = mbufA; float* mn = mbufB;
  for (int i = 0; i < NSTEP; i++) {
    k_ctrl<<<BATCH, 256, 0, stream>>>(cbuf, mc, Wci, bci,
                                      Wu + (size_t)i * DM * DM, bu + i * DM,
                                      caw, concepts, Wm, bm, cbuf, mp);
    k_prefold<<<dim3(8, 8, 4), 256, 0, stream>>>(Wcat, mp, befft);
    k_fused12<<<dim3(25, 32), 1024, FUSED_LDS, stream>>>(
        kproj, befft, wc2t, bcat, bcat2, cbuf, raw, rl);
    k_softinfo<<<dim3(BATCH, 8), 256, 0, stream>>>(rl, know, ipart);
    k_write<<<dim3(BATCH, 2), 256, 0, stream>>>(mc, ipart, Wwrite, bwrite, mn);
    float* tswap = mc; mc = mn; mn = tswap;
  }

  k_mpo<<<BATCH, 320, 0, stream>>>(mc, Wproj, bproj, oaw, mw);
  k_logits<<<dim3(BATCH, 4), 256, 0, stream>>>(mw, labels, logits);
  k_softmax_out<<<BATCH, 256, 0, stream>>>(logits, (float*)d_out);

  (void)in_sizes; (void)n_in; (void)out_size;
}

// Round 12
// 6999.188 us; speedup vs baseline: 1.1836x; 1.0476x over previous
//
#include <hip/hip_runtime.h>
#include <math.h>

#define DM    512
#define SP    1568   // 8*14*14
#define BATCH 32
#define NSTEP 12
#define CPAD  2560   // padded per-batch spatial rows (10*16*16)
#define LDT   40     // kproj-GEMM LDS row stride (bf16)
#define LDT2  72     // conv BK=64 LDS row stride (bf16)
#define ILS   520    // fused kernel LDS row stride (bf16)

typedef short s16x8 __attribute__((ext_vector_type(8)));
typedef float f32x4 __attribute__((ext_vector_type(4)));

__device__ __forceinline__ float eluf(float x) { return x > 0.f ? x : expf(x) - 1.f; }
__device__ __forceinline__ float b2f(ushort u) {
  union { float f; unsigned i; } v; v.i = ((unsigned)u) << 16; return v.f;
}
__device__ __forceinline__ ushort f2b(float f) {
  union { float f; unsigned i; } v; v.f = f;
  unsigned r = (v.i + 0x7FFFu + ((v.i >> 16) & 1u)) >> 16;
  return (ushort)r;
}

// ---------------------------------------------------------------------------
__global__ void k_zero(uint4* __restrict__ p, long n16) {
  long stride = (long)gridDim.x * blockDim.x;
  for (long i = (long)blockIdx.x * blockDim.x + threadIdx.x; i < n16; i += stride)
    p[i] = make_uint4(0, 0, 0, 0);
}

// image [32][256][1568] fp32 -> NHWC padded bf16 [b][2560][256] (interior only)
__global__ void k_padimg(const float* __restrict__ img, ushort* __restrict__ xp) {
  int blk = blockIdx.x;                 // 32*1568
  int b = blk / SP, s = blk - b * SP;
  int ci = threadIdx.x;                 // 256
  int z = s / 196, r = s - z * 196, y = r / 14, x = r - y * 14;
  int p = (z + 1) * 256 + (y + 1) * 16 + (x + 1);
  xp[((size_t)b * CPAD + p) * 256 + ci] = f2b(img[((size_t)b * 256 + ci) * SP + s]);
}

// conv weights [co][ci][27] fp32 -> tap-major bf16 [co][tap*CIN+ci]
template <int CIN>
__global__ void k_cvtw(const float* __restrict__ w, ushort* __restrict__ o) {
  int idx = blockIdx.x * 256 + threadIdx.x;   // < 512*27*CIN
  const int KK = 27 * CIN;
  int co = idx / KK; int rem = idx - co * KK;
  int tap = rem / CIN; int ci = rem - tap * CIN;
  o[idx] = f2b(w[((size_t)co * CIN + ci) * 27 + tap]);
}

// [512][512] fp32 -> transposed bf16 [n][k]
__global__ void k_cvtT(const float* __restrict__ w, ushort* __restrict__ o) {
  int idx = blockIdx.x * 256 + threadIdx.x;   // < 512*512
  int n = idx >> 9, k = idx & 511;
  o[idx] = f2b(w[(size_t)k * 512 + n]);
}

// ---------------------------------------------------------------------------
// MFMA conv3d, NHWC activations, BK=64 (unchanged)
// ---------------------------------------------------------------------------
template <int CIN, int ISCONV1>
__global__ __launch_bounds__(256) void k_convm(
    const ushort* __restrict__ W, const ushort* __restrict__ Xp,
    const float* __restrict__ bias, ushort* __restrict__ Y)
{
  const int KK = CIN * 27;
  const int b  = blockIdx.z;
  const int n0 = blockIdx.x * 128;
  const int m0 = blockIdx.y * 128;
  __shared__ __align__(16) ushort As[128 * LDT2];
  __shared__ __align__(16) ushort Bs[128 * LDT2];
  const int t = threadIdx.x;
  const int lane = t & 63, wid = t >> 6;
  const int wm = (wid >> 1) * 64, wn = (wid & 1) * 64;
  const int l15 = lane & 15, quad = lane >> 4;
  f32x4 acc[4][4];
#pragma unroll
  for (int i = 0; i < 4; i++)
#pragma unroll
    for (int j = 0; j < 4; j++) acc[i][j] = (f32x4){0.f, 0.f, 0.f, 0.f};

  for (int k0 = 0; k0 < KK; k0 += 64) {
#pragma unroll
    for (int i = 0; i < 4; i++) {          // A tile: 128co x 64k
      int f = t + i * 256;
      int row = f >> 3, ko = (f & 7) * 8;
      uint4 v = *(const uint4*)&W[(size_t)(m0 + row) * KK + k0 + ko];
      *(uint4*)&As[row * LDT2 + ko] = v;
    }
    {                                       // B tile: fixed tap, NHWC, 64 ci
      int tap = k0 / CIN, ci0 = k0 - tap * CIN;
      int dz = tap / 9, rr = tap - dz * 9, dy = rr / 3, dx = rr - dy * 3;
      int tofs = dz * 256 + dy * 16 + dx;
      const ushort* src = Xp + ((size_t)b * CPAD + tofs + n0) * CIN + ci0;
#pragma unroll
      for (int i = 0; i < 4; i++) {
        int f = t + i * 256;
        int row = f >> 3, ko = (f & 7) * 8;
        uint4 v = *(const uint4*)&src[(size_t)row * CIN + ko];
        *(uint4*)&Bs[row * LDT2 + ko] = v;
      }
    }
    __syncthreads();
#pragma unroll
    for (int sub = 0; sub < 2; sub++) {
      s16x8 af[4], bfr[4];
#pragma unroll
      for (int i = 0; i < 4; i++)
        af[i] = *(const s16x8*)&As[(wm + i * 16 + l15) * LDT2 + sub * 32 + quad * 8];
#pragma unroll
      for (int j = 0; j < 4; j++)
        bfr[j] = *(const s16x8*)&Bs[(wn + j * 16 + l15) * LDT2 + sub * 32 + quad * 8];
#pragma unroll
      for (int i = 0; i < 4; i++)
#pragma unroll
        for (int j = 0; j < 4; j++)
          acc[i][j] = __builtin_amdgcn_mfma_f32_16x16x32_bf16(af[i], bfr[j], acc[i][j], 0, 0, 0);
    }
    __syncthreads();
  }

#pragma unroll
  for (int i = 0; i < 4; i++) {
    int cob = m0 + wm + i * 16 + quad * 4;
    float4 bb = *(const float4*)&bias[cob];
#pragma unroll
    for (int j = 0; j < 4; j++) {
      int n = n0 + wn + j * 16 + l15;
      int z = n >> 8, y = (n >> 4) & 15, x = n & 15;
      if (y < 14 && x < 14) {
        ushort4 o;
        o.x = f2b(eluf(acc[i][j][0] + bb.x));
        o.y = f2b(eluf(acc[i][j][1] + bb.y));
        o.z = f2b(eluf(acc[i][j][2] + bb.z));
        o.w = f2b(eluf(acc[i][j][3] + bb.w));
        if (ISCONV1) {
          *(ushort4*)&Y[((size_t)b * CPAD + n + 273) * 512 + cob] = o;
        } else {
          int s = z * 196 + y * 14 + x;
          *(ushort4*)&Y[((size_t)b * SP + s) * DM + cob] = o;
        }
      }
    }
  }
}

// ---------------------------------------------------------------------------
// MFMA GEMM: kproj = know @ WkT + bk (unchanged)
// ---------------------------------------------------------------------------
__global__ __launch_bounds__(256) void k_gemmm(
    const ushort* __restrict__ A0, const ushort* __restrict__ Bt,
    const float* __restrict__ bias, ushort* __restrict__ Cv)
{
  const int bq = blockIdx.z;
  const int m0 = blockIdx.x * 128;
  const int n0 = blockIdx.y * 128;
  const ushort* A = A0 + (size_t)bq * SP * DM;
  __shared__ __align__(16) ushort As[128 * LDT];
  __shared__ __align__(16) ushort Bs[128 * LDT];
  const int t = threadIdx.x;
  const int lane = t & 63, wid = t >> 6;
  const int wm = (wid >> 1) * 64, wn = (wid & 1) * 64;
  const int l15 = lane & 15, quad = lane >> 4;
  f32x4 acc[4][4];
#pragma unroll
  for (int i = 0; i < 4; i++)
#pragma unroll
    for (int j = 0; j < 4; j++) acc[i][j] = (f32x4){0.f, 0.f, 0.f, 0.f};

  for (int k0 = 0; k0 < DM; k0 += 32) {
#pragma unroll
    for (int i = 0; i < 2; i++) {
      int f = t + i * 256;
      int row = f >> 2, ko = (f & 3) * 8;
      int mg = m0 + row;
      uint4 v = make_uint4(0, 0, 0, 0);
      if (mg < SP) v = *(const uint4*)&A[(size_t)mg * DM + k0 + ko];
      *(uint4*)&As[row * LDT + ko] = v;
      uint4 w = *(const uint4*)&Bt[(size_t)(n0 + row) * DM + k0 + ko];
      *(uint4*)&Bs[row * LDT + ko] = w;
    }
    __syncthreads();
    s16x8 af[4], bfr[4];
#pragma unroll
    for (int i = 0; i < 4; i++)
      af[i] = *(const s16x8*)&As[(wm + i * 16 + l15) * LDT + quad * 8];
#pragma unroll
    for (int j = 0; j < 4; j++)
      bfr[j] = *(const s16x8*)&Bs[(wn + j * 16 + l15) * LDT + quad * 8];
#pragma unroll
    for (int i = 0; i < 4; i++)
#pragma unroll
      for (int j = 0; j < 4; j++)
        acc[i][j] = __builtin_amdgcn_mfma_f32_16x16x32_bf16(af[i], bfr[j], acc[i][j], 0, 0, 0);
    __syncthreads();
  }

  ushort* C = Cv + (size_t)bq * SP * DM;
#pragma unroll
  for (int j = 0; j < 4; j++) {
    int n = n0 + wn + j * 16 + l15;
    float bb = bias[n];
#pragma unroll
    for (int i = 0; i < 4; i++) {
      int mb = m0 + wm + i * 16 + quad * 4;
#pragma unroll
      for (int r = 0; r < 4; r++) {
        int m = mb + r;
        if (m < SP) C[(size_t)m * DM + n] = f2b(acc[i][j][r] + bb);
      }
    }
  }
}

// ---------------------------------------------------------------------------
// Fused ReadUnit GEMM pair v8 — EXACT v4 structure (7.01 ms best-known:
// Af+Il in LDS, 16 waves, 137 KB, 4 waves/SIMD, stage A 64m x 16n/wave,
// stage B 64m x 32n/wave) + XCD-aware batch swizzle: 1-D grid of 800,
// tile%8 selects an XCD group that serves only 4 batches, so each XCD's L2
// holds 4 x 512KB befft + wc2t (~2.5 MB < 4 MB) instead of thrashing L3.
// ---------------------------------------------------------------------------
__global__ __launch_bounds__(1024, 4) void k_fused12(
    const ushort* __restrict__ kproj, const ushort* __restrict__ befft,
    const ushort* __restrict__ wc2t, const float* __restrict__ bcat,
    const float* __restrict__ bcat2, const float* __restrict__ cbuf,
    const float* __restrict__ raw, float* __restrict__ rl)
{
  extern __shared__ __align__(16) char smem[];
  ushort* Af  = (ushort*)smem;                 // 64*520 (kproj tile)
  ushort* Il  = Af + 64 * ILS;                 // 64*520 (inter1)
  float*  red = (float*)(Il + 64 * ILS);       // 64*16

  // XCD-aware decode: tile%8 = XCD group (round-robin heuristic);
  // each group covers batches 4g..4g+3 and all 25 m-tiles.
  const int tile = blockIdx.x;                 // 0..799
  const int g = tile & 7, r = tile >> 3;       // r in 0..99
  const int b  = g * 4 + (r / 25);
  const int m0 = (r % 25) * 64;
  const int t  = threadIdx.x;
  const int lane = t & 63, w = t >> 6;         // 16 waves
  const int l15 = lane & 15, quad = lane >> 4;

  const ushort* kpb = kproj + (size_t)b * SP * DM;
#pragma unroll
  for (int i = 0; i < 4; i++) {
    int f = t + i * 1024;                      // < 4096 uint4 chunks
    int row = f >> 6, ch = (f & 63) * 8;
    int mg = m0 + row;
    uint4 v = make_uint4(0, 0, 0, 0);
    if (mg < SP) v = *(const uint4*)&kpb[(size_t)mg * DM + ch];
    *(uint4*)&Af[row * ILS + ch] = v;
  }
  __syncthreads();

  // ---- stage A: 2 strips x 16 k-chunks, no internal barriers ----
  const ushort* bfb = befft + (size_t)b * DM * DM;
#pragma unroll 1
  for (int p = 0; p < 2; p++) {
    const int n1 = p * 256 + w * 16 + l15;
    f32x4 acc[4];
#pragma unroll
    for (int i = 0; i < 4; i++) acc[i] = (f32x4){0.f, 0.f, 0.f, 0.f};
#pragma unroll 4
    for (int k0 = 0; k0 < DM; k0 += 32) {
      s16x8 bf = *(const s16x8*)&bfb[(size_t)n1 * DM + k0 + quad * 8];
#pragma unroll
      for (int i = 0; i < 4; i++) {
        s16x8 af = *(const s16x8*)&Af[(i * 16 + l15) * ILS + k0 + quad * 8];
        acc[i] = __builtin_amdgcn_mfma_f32_16x16x32_bf16(af, bf, acc[i], 0, 0, 0);
      }
    }
    float bc = bcat[n1];
#pragma unroll
    for (int i = 0; i < 4; i++)
#pragma unroll
      for (int r2 = 0; r2 < 4; r2++)
        Il[(i * 16 + quad * 4 + r2) * ILS + n1] = f2b(eluf(acc[i][r2] + bc));
  }
  __syncthreads();

  // ---- stage B: 16 k-chunks; each wave covers n2 = w*32 .. w*32+31 ----
  f32x4 acc2[4][2];
#pragma unroll
  for (int i = 0; i < 4; i++)
#pragma unroll
    for (int j = 0; j < 2; j++) acc2[i][j] = (f32x4){0.f, 0.f, 0.f, 0.f};
#pragma unroll 2
  for (int kk = 0; kk < DM; kk += 32) {
    s16x8 af[4], bf[2];
#pragma unroll
    for (int i = 0; i < 4; i++)
      af[i] = *(const s16x8*)&Il[(i * 16 + l15) * ILS + kk + quad * 8];
#pragma unroll
    for (int j = 0; j < 2; j++)
      bf[j] = *(const s16x8*)&wc2t[(size_t)(w * 32 + j * 16 + l15) * DM + kk + quad * 8];
#pragma unroll
    for (int i = 0; i < 4; i++)
#pragma unroll
      for (int j = 0; j < 2; j++)
        acc2[i][j] = __builtin_amdgcn_mfma_f32_16x16x32_bf16(af[i], bf[j], acc2[i][j], 0, 0, 0);
  }

  // ---- epilogue: rl[m] = sum_n elu((acc2 + bcat2)*c)*raw ----
  float epi[16];
#pragma unroll
  for (int e = 0; e < 16; e++) epi[e] = 0.f;
#pragma unroll
  for (int j = 0; j < 2; j++) {
    int n2 = w * 32 + j * 16 + l15;
    float b2 = bcat2[n2], cc = cbuf[(size_t)b * DM + n2], rw = raw[n2];
#pragma unroll
    for (int i = 0; i < 4; i++)
#pragma unroll
      for (int r2 = 0; r2 < 4; r2++)
        epi[i * 4 + r2] += eluf((acc2[i][j][r2] + b2) * cc) * rw;
  }
#pragma unroll
  for (int d2 = 1; d2 < 16; d2 <<= 1)
#pragma unroll
    for (int e = 0; e < 16; e++) epi[e] += __shfl_xor(epi[e], d2, 64);
  if (l15 == 0) {
#pragma unroll
    for (int i = 0; i < 4; i++)
#pragma unroll
      for (int r2 = 0; r2 < 4; r2++)
        red[(i * 16 + quad * 4 + r2) * 16 + w] = epi[i * 4 + r2];
  }
  __syncthreads();
  if (t < 64) {
    int m = m0 + t;
    if (m < SP) {
      float s = 0.f;
#pragma unroll
      for (int q = 0; q < 16; q++) s += red[t * 16 + q];
      rl[(size_t)b * SP + m] = s;
    }
  }
}

// ---------------------------------------------------------------------------
// Per-step fold: befft[b][n][k] = bf16(mp[b][k]*Wcat[k][n] + Wcat[512+k][n])
// ---------------------------------------------------------------------------
__global__ __launch_bounds__(256) void k_prefold(
    const float* __restrict__ Wcat, const float* __restrict__ mp,
    ushort* __restrict__ Bf)
{
  const int k0 = blockIdx.x * 64, n0 = blockIdx.y * 64;
  const int bbase = blockIdx.z * 8;
  __shared__ float S1[64][68], S2[64][68];
  const int t = threadIdx.x;
#pragma unroll
  for (int i = 0; i < 4; i++) {
    int f = t + i * 256;
    int kk = f >> 4, nn2 = (f & 15) * 4;
    float4 a = *(const float4*)&Wcat[(size_t)(k0 + kk) * DM + n0 + nn2];
    float4 c = *(const float4*)&Wcat[(size_t)(DM + k0 + kk) * DM + n0 + nn2];
    *(float4*)&S1[kk][nn2] = a;
    *(float4*)&S2[kk][nn2] = c;
  }
  __syncthreads();
  const int n = t >> 2, kseg = (t & 3) * 16;
  for (int bq = 0; bq < 8; bq++) {
    const float* mpb = mp + (size_t)(bbase + bq) * DM + k0 + kseg;
    ushort* out = Bf + ((size_t)(bbase + bq) * DM + n0 + n) * DM + k0 + kseg;
#pragma unroll
    for (int g = 0; g < 4; g++) {
      ushort4 o;
      o.x = f2b(mpb[g * 4 + 0] * S1[kseg + g * 4 + 0][n] + S2[kseg + g * 4 + 0][n]);
      o.y = f2b(mpb[g * 4 + 1] * S1[kseg + g * 4 + 1][n] + S2[kseg + g * 4 + 1][n]);
      o.z = f2b(mpb[g * 4 + 2] * S1[kseg + g * 4 + 2][n] + S2[kseg + g * 4 + 2][n]);
      o.w = f2b(mpb[g * 4 + 3] * S1[kseg + g * 4 + 3][n] + S2[kseg + g * 4 + 3][n]);
      *(ushort4*)&out[g * 4] = o;
    }
  }
}

// ---------------------------------------------------------------------------
// Control unit (unchanged)
// ---------------------------------------------------------------------------
__global__ __launch_bounds__(256) void k_ctrl(
    const float* cin, const float* __restrict__ min_,
    const float* __restrict__ Wci, const float* __restrict__ bci,
    const float* __restrict__ Wu_i, const float* __restrict__ bu_i,
    const float* __restrict__ caw, const float* __restrict__ concepts,
    const float* __restrict__ Wm, const float* __restrict__ bm,
    float* cout, float* __restrict__ mpout)
{
  const int b = blockIdx.x, t = threadIdx.x;
  __shared__ float sc[512], sm[512], sq0[512], sqa[512], scl[80], red[256];
  sc[t] = cin[b * DM + t];       sc[t + 256] = cin[b * DM + t + 256];
  sm[t] = min_[b * DM + t];      sm[t + 256] = min_[b * DM + t + 256];
  __syncthreads();
#pragma unroll
  for (int h = 0; h < 2; h++) {
    int d = t + h * 256;
    float a = bci[d];
    for (int k = 0; k < 512; k++) a = fmaf(sc[k], Wci[k * DM + d], a);
    for (int k = 0; k < 512; k++) a = fmaf(sm[k], Wci[(512 + k) * DM + d], a);
    sq0[d] = tanhf(a);
    float mpa = bm[d];
    for (int k = 0; k < 512; k++) mpa = fmaf(sm[k], Wm[k * DM + d], mpa);
    mpout[b * DM + d] = mpa;
  }
  __syncthreads();
#pragma unroll
  for (int h = 0; h < 2; h++) {
    int d = t + h * 256;
    float a = bu_i[d];
    for (int k = 0; k < 512; k++) a = fmaf(sq0[k], Wu_i[k * DM + d], a);
    sqa[d] = a * caw[d];
  }
  __syncthreads();
  float myl = -INFINITY;
  if (t < 80) {
    float a = 0.f;
    for (int d = 0; d < 512; d++) a = fmaf(sqa[d], concepts[t * DM + d], a);
    scl[t] = a; myl = a;
  }
  red[t] = myl; __syncthreads();
  for (int s = 128; s > 0; s >>= 1) { if (t < s) red[t] = fmaxf(red[t], red[t + s]); __syncthreads(); }
  float mx = red[0]; __syncthreads();
  float e = 0.f;
  if (t < 80) e = expf(scl[t] - mx);
  red[t] = e; __syncthreads();
  for (int s = 128; s > 0; s >>= 1) { if (t < s) red[t] += red[t + s]; __syncthreads(); }
  float inv = 1.f / red[0]; __syncthreads();
  if (t < 80) scl[t] = e * inv;
  __syncthreads();
#pragma unroll
  for (int h = 0; h < 2; h++) {
    int d = t + h * 256;
    float a = 0.f;
    for (int l = 0; l < 80; l++) a = fmaf(scl[l], concepts[l * DM + d], a);
    cout[b * DM + d] = a;
  }
}

// ---------------------------------------------------------------------------
// Fused read softmax + info partial (unchanged)
// ---------------------------------------------------------------------------
__global__ __launch_bounds__(256) void k_softinfo(
    const float* __restrict__ rl, const ushort* __restrict__ know,
    float* __restrict__ ipart)
{
  const int b = blockIdx.x, c = blockIdx.y, t = threadIdx.x;
  __shared__ float red[256];
  float vals[7]; float vmax = -INFINITY;
#pragma unroll
  for (int q = 0; q < 7; q++) {
    int s = t + q * 256;
    float v = (s < SP) ? rl[(size_t)b * SP + s] : -INFINITY;
    vals[q] = v; vmax = fmaxf(vmax, v);
  }
  red[t] = vmax; __syncthreads();
  for (int s = 128; s > 0; s >>= 1) { if (t < s) red[t] = fmaxf(red[t], red[t + s]); __syncthreads(); }
  float mx = red[0]; __syncthreads();
  float lsum = 0.f;
#pragma unroll
  for (int q = 0; q < 7; q++) {
    int s = t + q * 256;
    lsum += (s < SP) ? expf(vals[q] - mx) : 0.f;
  }
  red[t] = lsum; __syncthreads();
  for (int s = 128; s > 0; s >>= 1) { if (t < s) red[t] += red[t + s]; __syncthreads(); }
  float inv = 1.f / red[0];

  float a0 = 0.f, a1 = 0.f;
  const ushort* kb = know + (size_t)b * SP * DM + 2 * t;
  const float* rlb = rl + (size_t)b * SP;
  for (int s = c * 196; s < (c + 1) * 196; s++) {
    float r = expf(rlb[s] - mx) * inv;
    ushort2 kv = *(const ushort2*)&kb[(size_t)s * DM];
    a0 = fmaf(r, b2f(kv.x), a0);
    a1 = fmaf(r, b2f(kv.y), a1);
  }
  ipart[((size_t)b * 8 + c) * DM + 2 * t] = a0;
  ipart[((size_t)b * 8 + c) * DM + 2 * t + 1] = a1;
}

// m_new = [m_old, info] @ Wwrite + bwrite
__global__ __launch_bounds__(256) void k_write(
    const float* __restrict__ mold, const float* __restrict__ ipart,
    const float* __restrict__ Ww, const float* __restrict__ bw,
    float* __restrict__ mnew)
{
  const int b = blockIdx.x, half = blockIdx.y, t = threadIdx.x;
  __shared__ float smo[512], sinfo[512];
  for (int k = t; k < 512; k += 256) {
    smo[k] = mold[b * DM + k];
    float s = 0.f;
    for (int c = 0; c < 8; c++) s += ipart[((size_t)b * 8 + c) * DM + k];
    sinfo[k] = s;
  }
  __syncthreads();
  int d = half * 256 + t;
  float a = bw[d];
  for (int k = 0; k < 512; k++) a = fmaf(smo[k], Ww[k * DM + d], a);
  for (int k = 0; k < 512; k++) a = fmaf(sinfo[k], Ww[(512 + k) * DM + d], a);
  mnew[b * DM + d] = a;
}

__global__ void k_init(const float* __restrict__ initc, const float* __restrict__ initm,
                       float* __restrict__ cbuf, float* __restrict__ mbuf)
{
  const int b = blockIdx.x, t = threadIdx.x;
  cbuf[b * DM + t] = initc[t];
  mbuf[b * DM + t] = initm[t];
}

__global__ void k_mpo(const float* __restrict__ m, const float* __restrict__ Wproj,
                      const float* __restrict__ bproj, const float* __restrict__ ow,
                      float* __restrict__ mw)
{
  const int b = blockIdx.x, t = threadIdx.x;
  __shared__ float smem[512];
  for (int k = t; k < 512; k += 320) smem[k] = m[b * DM + k];
  __syncthreads();
  if (t < 300) {
    float a = bproj[t];
    for (int k = 0; k < 512; k++) a = fmaf(smem[k], Wproj[k * 300 + t], a);
    mw[b * 300 + t] = a * ow[t];
  }
}

__global__ void k_logits(const float* __restrict__ mw, const float* __restrict__ labels,
                         float* __restrict__ logits)
{
  const int b = blockIdx.x, t = threadIdx.x;
  const int a = blockIdx.y * 256 + t;
  __shared__ float smw[300];
  for (int p = t; p < 300; p += 256) smw[p] = mw[b * 300 + p];
  __syncthreads();
  if (a < 1000) {
    float acc = 0.f;
    for (int p = 0; p < 300; p++) acc = fmaf(smw[p], labels[a * 300 + p], acc);
    logits[b * 1000 + a] = acc;
  }
}

__global__ void k_softmax_out(const float* __restrict__ logits, float* __restrict__ out)
{
  const int b = blockIdx.x, t = threadIdx.x;
  __shared__ float red[256];
  float v[4]; float vmax = -INFINITY;
#pragma unroll
  for (int q = 0; q < 4; q++) {
    int a = t + q * 256;
    v[q] = (a < 1000) ? logits[b * 1000 + a] : -INFINITY;
    vmax = fmaxf(vmax, v[q]);
  }
  red[t] = vmax; __syncthreads();
  for (int s = 128; s > 0; s >>= 1) { if (t < s) red[t] = fmaxf(red[t], red[t + s]); __syncthreads(); }
  float mx = red[0]; __syncthreads();
  float lsum = 0.f;
#pragma unroll
  for (int q = 0; q < 4; q++) {
    int a = t + q * 256;
    v[q] = (a < 1000) ? expf(v[q] - mx) : 0.f;
    lsum += v[q];
  }
  red[t] = lsum; __syncthreads();
  for (int s = 128; s > 0; s >>= 1) { if (t < s) red[t] += red[t + s]; __syncthreads(); }
  float inv = 1.f / red[0];
#pragma unroll
  for (int q = 0; q < 4; q++) {
    int a = t + q * 256;
    if (a < 1000) out[b * 1000 + a] = v[q] * inv;
  }
}

// ---------------------------------------------------------------------------
extern "C" void kernel_launch(void* const* d_in, const int* in_sizes, int n_in,
                              void* d_out, int out_size, void* d_ws, size_t ws_size,
                              hipStream_t stream)
{
  const float* image    = (const float*)d_in[0];
  const float* concepts = (const float*)d_in[1];
  const float* conv1_w  = (const float*)d_in[2];
  const float* conv1_b  = (const float*)d_in[3];
  const float* conv2_w  = (const float*)d_in[4];
  const float* conv2_b  = (const float*)d_in[5];
  const float* Wci      = (const float*)d_in[6];
  const float* bci      = (const float*)d_in[7];
  const float* Wu       = (const float*)d_in[8];
  const float* bu       = (const float*)d_in[9];
  const float* caw      = (const float*)d_in[10];
  const float* Wk       = (const float*)d_in[12];
  const float* bk       = (const float*)d_in[13];
  const float* Wm       = (const float*)d_in[14];
  const float* bm       = (const float*)d_in[15];
  const float* Wcat     = (const float*)d_in[16];
  const float* bcat     = (const float*)d_in[17];
  const float* Wcat2    = (const float*)d_in[18];
  const float* bcat2    = (const float*)d_in[19];
  const float* raw      = (const float*)d_in[20];
  const float* Wwrite   = (const float*)d_in[22];
  const float* bwrite   = (const float*)d_in[23];
  const float* initc    = (const float*)d_in[24];
  const float* initm    = (const float*)d_in[25];
  const float* Wproj    = (const float*)d_in[26];
  const float* bproj    = (const float*)d_in[27];
  const float* oaw      = (const float*)d_in[28];
  const float* labels   = (const float*)d_in[30];

  char* ws = (char*)d_ws;
  const size_t OFF_KNOW = 0;
  const size_t OFF_XPAD = 51380224;
  const size_t SZ_XPAD  = 83951616;
  const size_t OFF_W    = OFF_XPAD + SZ_XPAD;
  const size_t OFF_WKT  = OFF_W + 14155776;
  const size_t OFF_WC2T = OFF_WKT + 524288;
  size_t off = OFF_WC2T + 524288;
  auto allocB = [&](size_t bytes) {
    void* p = ws + off; off += (bytes + 255) & ~(size_t)255; return p;
  };
  ushort* know   = (ushort*)(ws + OFF_KNOW);
  ushort* imgpad = (ushort*)(ws + OFF_KNOW);                 // stem only
  ushort* xpad1  = (ushort*)(ws + OFF_XPAD);                 // stem only
  ushort* kproj  = (ushort*)(ws + OFF_XPAD);                 // loop
  ushort* befft  = (ushort*)(ws + OFF_XPAD + 51380224);      // loop, 16.78MB
  float*  rl     = (float*) (ws + OFF_XPAD + 68157440);      // loop, 0.2MB
  ushort* w1b    = (ushort*)(ws + OFF_W);
  ushort* w2b    = (ushort*)(ws + OFF_W);
  ushort* wkt    = (ushort*)(ws + OFF_WKT);
  ushort* wc2t   = (ushort*)(ws + OFF_WC2T);
  float* ipart  = (float*)allocB((size_t)BATCH * 8 * DM * 4);
  float* cbuf   = (float*)allocB(BATCH * DM * 4);
  float* mbufA  = (float*)allocB(BATCH * DM * 4);
  float* mbufB  = (float*)allocB(BATCH * DM * 4);
  float* mp     = (float*)allocB(BATCH * DM * 4);
  float* mw     = (float*)allocB(BATCH * 300 * 4);
  float* logits = (float*)allocB(BATCH * 1000 * 4);
  if (off > ws_size) return;  // graceful fail

  const int FUSED_LDS = 64 * ILS * 2 * 2 + 64 * 16 * 4;  // 137,216 B (v4)
  hipFuncSetAttribute((const void*)k_fused12,
                      hipFuncAttributeMaxDynamicSharedMemorySize, FUSED_LDS);

  // --- stem ---
  k_zero<<<4096, 256, 0, stream>>>((uint4*)imgpad, 2625536L);
  k_zero<<<4096, 256, 0, stream>>>((uint4*)xpad1, 5246976L);
  k_padimg<<<BATCH * SP, 256, 0, stream>>>(image, imgpad);
  k_cvtw<256><<<13824, 256, 0, stream>>>(conv1_w, w1b);
  k_cvtT<<<1024, 256, 0, stream>>>(Wk, wkt);
  k_cvtT<<<1024, 256, 0, stream>>>(Wcat2, wc2t);
  k_convm<256, 1><<<dim3(16, 4, 32), 256, 0, stream>>>(w1b, imgpad, conv1_b, xpad1);
  k_cvtw<512><<<27648, 256, 0, stream>>>(conv2_w, w2b);
  k_convm<512, 0><<<dim3(16, 4, 32), 256, 0, stream>>>(w2b, xpad1, conv2_b, know);
  k_gemmm<<<dim3(13, 4, 32), 256, 0, stream>>>(know, wkt, bk, kproj);
  k_init<<<BATCH, DM, 0, stream>>>(initc, initm, cbuf, mbufA);

  float* mc = mbufA; float* mn = mbufB;
  for (int i = 0; i < NSTEP; i++) {
    k_ctrl<<<BATCH, 256, 0, stream>>>(cbuf, mc, Wci, bci,
                                      Wu + (size_t)i * DM * DM, bu + i * DM,
                                      caw, concepts, Wm, bm, cbuf, mp);
    k_prefold<<<dim3(8, 8, 4), 256, 0, stream>>>(Wcat, mp, befft);
    k_fused12<<<dim3(800), 1024, FUSED_LDS, stream>>>(
        kproj, befft, wc2t, bcat, bcat2, cbuf, raw, rl);
    k_softinfo<<<dim3(BATCH, 8), 256, 0, stream>>>(rl, know, ipart);
    k_write<<<dim3(BATCH, 2), 256, 0, stream>>>(mc, ipart, Wwrite, bwrite, mn);
    float* tswap = mc; mc = mn; mn = tswap;
  }

  k_mpo<<<BATCH, 320, 0, stream>>>(mc, Wproj, bproj, oaw, mw);
  k_logits<<<dim3(BATCH, 4), 256, 0, stream>>>(mw, labels, logits);
  k_softmax_out<<<BATCH, 256, 0, stream>>>(logits, (float*)d_out);

  (void)in_sizes; (void)n_in; (void)out_size;
}